// Round 1
// baseline (2242.630 us; speedup 1.0000x reference)
//
#include <hip/hip_runtime.h>
#include <math.h>

#define NZ 32
#define NY 360
#define NX 720
#define NXU (NX + 1)   // 721 (u x-extent)
#define NYV (NY + 1)   // 361 (v y-extent / G rows)

static constexpr double PI_D = 3.14159265358979323846;
static constexpr double RE_D = 6400000.0;
static constexpr double DX_D = 2.0 * PI_D / NX;
static constexpr double DY_D = PI_D / NY;
static constexpr double DA_D = RE_D * DX_D * (RE_D * DY_D);

constexpr float FXC   = (float)(0.25 * RE_D * DY_D);  // Fx = FXC*(pi[xm]+pi[x])*u
constexpr float GXC   = (float)(0.25 * RE_D * DX_D);  // G  = GXC*(pi[ym]+pi[y])*v*cosY
constexpr float DAF   = (float)DA_D;
constexpr float DA8F  = (float)(DA_D / 8.0);
constexpr float DYF   = (float)DY_D;
constexpr float DXF   = (float)DX_D;
constexpr float CPDF  = 1004.67f;
constexpr float DIFFF = 1.0e9f;
constexpr float RDZF  = 32.0f;    // 1/DZ
constexpr float DZF   = 0.03125f; // DZ

__device__ __forceinline__ int wr(int i, int n) {
    // wrap for i in [-1, n+1]
    return i < 0 ? i + n : (i >= n ? i - n : i);
}

// Fx(z,y,x): y in [0,NY), x in [0,NX]
__device__ __forceinline__ float fx_at(const float* __restrict__ pi, const float* __restrict__ u,
                                       int z, int y, int x) {
    float pib = pi[y * NX + wr(x - 1, NX)] + pi[y * NX + wr(x, NX)];
    return FXC * pib * u[(z * NY + y) * NXU + x];
}

// G(z,y,x): y in [0,NY], x in [0,NX)
__device__ __forceinline__ float g_at(const float* __restrict__ pi, const float* __restrict__ v,
                                      const float* __restrict__ cy, int z, int y, int x) {
    float pib = pi[wr(y - 1, NY) * NX + x] + pi[wr(y, NY) * NX + x];
    return GXC * pib * v[(z * NYV + y) * NX + x] * cy[y];
}

__global__ void k_cosy(const float* __restrict__ Y, float* __restrict__ cy) {
    int t = threadIdx.x;
    if (t < NYV) cy[t] = cosf(Y[t]);
}

// pi1[y,x] = pi0 - dt/DA * sum_z((dFx + dG)*DZ)
__global__ void k_pi1(const float* __restrict__ pi, const float* __restrict__ u,
                      const float* __restrict__ v, const float* __restrict__ cy,
                      const float* __restrict__ pi0, const float* __restrict__ dtp,
                      float dtmul, float* __restrict__ out) {
    int x = blockIdx.x * blockDim.x + threadIdx.x;
    int y = blockIdx.y;
    if (x >= NX) return;
    float dt = dtp[0] * dtmul;
    int xm = wr(x - 1, NX), xp = wr(x + 1, NX);
    float pc  = pi[y * NX + x];
    float a_m = pi[y * NX + xm] + pc;
    float a_p = pc + pi[y * NX + xp];
    float g_lo = (pi[wr(y - 1, NY) * NX + x] + pc) * cy[y];
    float g_hi = (pc + pi[wr(y + 1, NY) * NX + x]) * cy[y + 1];
    float acc = 0.f;
    for (int z = 0; z < NZ; ++z) {
        float fxm = FXC * a_m * u[(z * NY + y) * NXU + x];
        float fxp = FXC * a_p * u[(z * NY + y) * NXU + x + 1];
        float glo = GXC * g_lo * v[(z * NYV + y) * NX + x];
        float ghi = GXC * g_hi * v[(z * NYV + y + 1) * NX + x];
        acc += ((fxp - fxm) + (ghi - glo)) * DZF;
    }
    out[y * NX + x] = pi0[y * NX + x] - dt / DAF * acc;
}

__global__ void k_theta1(const float* __restrict__ pi, const float* __restrict__ th,
                         const float* __restrict__ u, const float* __restrict__ v,
                         const float* __restrict__ cy, const float* __restrict__ w,
                         const float* __restrict__ pi0, const float* __restrict__ th0,
                         const float* __restrict__ pi1, const float* __restrict__ dtp,
                         float dtmul, float* __restrict__ out) {
    int x = blockIdx.x * blockDim.x + threadIdx.x;
    if (x >= NX) return;
    int y = blockIdx.y, z = blockIdx.z;
    float dt = dtp[0] * dtmul;
    int idx = (z * NY + y) * NX + x;
    int xm = wr(x - 1, NX), xp = wr(x + 1, NX);
    int ym = wr(y - 1, NY), yp = wr(y + 1, NY);
    float thc   = th[idx];
    float th_xm = th[(z * NY + y) * NX + xm], th_xp = th[(z * NY + y) * NX + xp];
    float th_ym = th[(z * NY + ym) * NX + x], th_yp = th[(z * NY + yp) * NX + x];
    float fx0 = fx_at(pi, u, z, y, x), fx1 = fx_at(pi, u, z, y, x + 1);
    float g0  = g_at(pi, v, cy, z, y, x), g1 = g_at(pi, v, cy, z, y + 1, x);
    float adv = (fx1 * 0.5f * (thc + th_xp) - fx0 * 0.5f * (th_xm + thc)
               + g1  * 0.5f * (thc + th_yp) - g0  * 0.5f * (th_ym + thc)) * 0.5f;
    float vert = pi[y * NX + x] * DAF * (w[idx] * th0[idx]) * RDZF;
    float lap = (z + 1 < NZ ? th[idx + NY * NX] : 0.f) + (z > 0 ? th[idx - NY * NX] : 0.f)
              + th_yp + th_ym + th_xp + th_xm - 6.0f * thc;
    float p1 = pi1[y * NX + x];
    out[idx] = pi0[y * NX + x] / p1 * th0[idx] + dt / DAF / p1 * (adv + vert + DIFFF * lap);
}

__global__ void k_u1(const float* __restrict__ pi, const float* __restrict__ th,
                     const float* __restrict__ u, const float* __restrict__ v,
                     const float* __restrict__ cy, const float* __restrict__ w,
                     const float* __restrict__ phi, const float* __restrict__ pi0,
                     const float* __restrict__ u0, const float* __restrict__ pi1,
                     const float* __restrict__ sigma, const float* __restrict__ Pu,
                     const float* __restrict__ Pp, const float* __restrict__ dtp,
                     float dtmul, float* __restrict__ out) {
    int x = blockIdx.x * blockDim.x + threadIdx.x;
    if (x >= NXU) return;
    int y = blockIdx.y, z = blockIdx.z;
    float dt = dtp[0] * dtmul;
    int x0 = wr(x, NX), xm = wr(x - 1, NX);
    int ym = wr(y - 1, NY), yp = wr(y + 1, NY);

    auto FX = [&](int yy, int xx) { return fx_at(pi, u, z, yy, xx); };
    auto GG = [&](int yy, int xx) { return g_at(pi, v, cy, z, yy, xx); };

    // B(yy,xx): xx in [0,NX)
    auto B = [&](int yy, int xx) {
        int a = wr(yy - 1, NY), b = wr(yy + 1, NY);
        return 0.25f * (FX(a, xx) + FX(a, xx + 1) + FX(b, xx) + FX(b, xx + 1)) * (1.0f / 12.0f);
    };
    auto UB = [&](int yy, int xx) {
        return 0.5f * (u[(z * NY + yy) * NXU + xx] + u[(z * NY + yy) * NXU + xx + 1]);
    };
    float term1 = -(B(y, x0) * UB(y, x0) - B(y, xm) * UB(y, xm));

    // C(yy,xx): yy in [0,NY], xx in [0,NX]
    auto C = [&](int yy, int xx) {
        int a = wr(yy - 1, NYV), b = wr(yy + 1, NYV);
        int cm = wr(xx - 1, NX), c0 = wr(xx, NX);
        return 0.25f * (GG(a, cm) + GG(a, c0) + GG(b, cm) + GG(b, c0)) * (1.0f / 12.0f);
    };
    auto UY = [&](int yy, int xx) { // bar_y(pad_y(u))
        return 0.5f * (u[(z * NY + wr(yy - 1, NY)) * NXU + xx] + u[(z * NY + wr(yy, NY)) * NXU + xx]);
    };
    float term2 = -(C(y + 1, x) * UY(y + 1, x) - C(y, x) * UY(y, x));

    // D/E(yy,xx): yy in [0,NY], xx in [0,NX)
    auto DE = [&](int yy, int xx, float& Dv, float& Ev) {
        int a2 = wr(yy - 1, NYV), b2 = wr(yy + 1, NYV);
        float gpart = 0.5f * (GG(a2, xx) + GG(b2, xx));
        int am = wr(yy - 1, NY), a0 = wr(yy, NY);
        float fpart = 0.25f * (FX(am, xx) + FX(am, xx + 1) + FX(a0, xx) + FX(a0, xx + 1)) * (1.0f / 24.0f);
        Dv = gpart + fpart;
        Ev = gpart - fpart;
    };
    auto UXY = [&](int yy, int xx) { // bar_xy(pad_y(u)), xx in [0,NX)
        int am = wr(yy - 1, NY), a0 = wr(yy, NY);
        return 0.25f * (u[(z * NY + am) * NXU + xx] + u[(z * NY + am) * NXU + xx + 1]
                      + u[(z * NY + a0) * NXU + xx] + u[(z * NY + a0) * NXU + xx + 1]);
    };
    float D_a, E_a, D_b, E_b, D_c, E_c, D_d, E_d;
    DE(y + 1, x0, D_a, E_a);
    DE(y,     xm, D_b, E_b);
    DE(y + 1, xm, D_c, E_c);
    DE(y,     x0, D_d, E_d);
    float term3 = D_a * UXY(y + 1, x0) - D_b * UXY(y, xm);
    float term4 = E_c * UXY(y + 1, xm) - E_d * UXY(y, x0);
    float advec = 0.5f * (term1 + term2 + term3 + term4);

    // trans
    float pw = pi[ym * NX + xm] * w[(z * NY + ym) * NX + xm]
             + pi[ym * NX + x0] * w[(z * NY + ym) * NX + x0]
             + pi[yp * NX + xm] * w[(z * NY + yp) * NX + xm]
             + pi[yp * NX + x0] * w[(z * NY + yp) * NX + x0];
    float piw = DA8F * 0.25f * pw;
    float ubz = 0.5f * ((z > 0 ? u[((z - 1) * NY + y) * NXU + x] : 0.f)
                      + (z + 1 < NZ ? u[((z + 1) * NY + y) * NXU + x] : 0.f));
    float trans = -(piw * ubz * 0.5f) * RDZF;

    // press
    float dphi = phi[(z * NY + y) * NX + x0] - phi[(z * NY + y) * NX + xm];
    float dpi  = pi[y * NX + x0] - pi[y * NX + xm];
    float vc   = (sigma[z] * Pu[z] - Pp[z] * sigma[z]) * RDZF;
    float vbar = 0.5f * (th[(z * NY + y) * NX + xm] + th[(z * NY + y) * NX + x0]) * vc;
    float press = DYF * (dphi * dpi * 0.5f + dpi * 0.5f * CPDF * vbar);

    // diff: laplacian of u, x wraps over NXU
    int xum = wr(x - 1, NXU), xup = wr(x + 1, NXU);
    float uc = u[(z * NY + y) * NXU + x];
    float lap = (z + 1 < NZ ? u[((z + 1) * NY + y) * NXU + x] : 0.f)
              + (z > 0 ? u[((z - 1) * NY + y) * NXU + x] : 0.f)
              + u[(z * NY + yp) * NXU + x] + u[(z * NY + ym) * NXU + x]
              + u[(z * NY + y) * NXU + xup] + u[(z * NY + y) * NXU + xum] - 6.0f * uc;
    float diffv = DIFFF * lap;

    float p0da = DA8F * 0.25f * (pi0[ym * NX + xm] + pi0[ym * NX + x0] + pi0[yp * NX + xm] + pi0[yp * NX + x0]);
    float p1da = DA8F * 0.25f * (pi1[ym * NX + xm] + pi1[ym * NX + x0] + pi1[yp * NX + xm] + pi1[yp * NX + x0]);
    out[(z * NY + y) * NXU + x] = (p0da * u0[(z * NY + y) * NXU + x] + dt * (advec + trans + press + diffv)) / p1da;
}

__global__ void k_v1(const float* __restrict__ pi, const float* __restrict__ th,
                     const float* __restrict__ u, const float* __restrict__ v,
                     const float* __restrict__ cy, const float* __restrict__ w,
                     const float* __restrict__ phi, const float* __restrict__ pi0,
                     const float* __restrict__ v0, const float* __restrict__ pi1,
                     const float* __restrict__ sigma, const float* __restrict__ Pu,
                     const float* __restrict__ Pp, const float* __restrict__ dtp,
                     float dtmul, float* __restrict__ out) {
    int x = blockIdx.x * blockDim.x + threadIdx.x;
    if (x >= NX) return;
    int y = blockIdx.y, z = blockIdx.z; // y in [0,NY]
    float dt = dtp[0] * dtmul;
    int xm = wr(x - 1, NX), xp = wr(x + 1, NX);
    int y0 = wr(y, NY), ym = wr(y - 1, NY);

    auto FX = [&](int yy, int xx) { return fx_at(pi, u, z, yy, xx); };
    auto GG = [&](int yy, int xx) { return g_at(pi, v, cy, z, yy, xx); };

    // Q(yy,xx): yy in [0,NY], xx in [0,NX]
    auto Q = [&](int yy, int xx) {
        int a = wr(yy - 1, NY), b = wr(yy, NY);
        int cm = wr(xx - 1, NXU), cp = wr(xx + 1, NXU);
        return 0.25f * (FX(a, cm) + FX(b, cm) + FX(a, cp) + FX(b, cp)) * (1.0f / 12.0f);
    };
    auto VX = [&](int yy, int xx) { // bar_x(pad_x(v))
        return 0.5f * (v[(z * NYV + yy) * NX + wr(xx - 1, NX)] + v[(z * NYV + yy) * NX + wr(xx, NX)]);
    };
    float term1 = -(Q(y, x + 1) * VX(y, x + 1) - Q(y, x) * VX(y, x));

    // R(yy,xx): yy in [0,NY), xx in [0,NX)
    auto Rf = [&](int yy, int xx) {
        int cm = wr(xx - 1, NX), cp2 = wr(xx + 1, NX);
        return 0.25f * (GG(yy, cm) + GG(yy + 1, cm) + GG(yy, cp2) + GG(yy + 1, cp2)) * (1.0f / 12.0f);
    };
    auto VY = [&](int yy, int xx) { return 0.5f * (v[(z * NYV + yy) * NX + xx] + v[(z * NYV + yy + 1) * NX + xx]); };
    float term2 = -(Rf(y0, x) * VY(y0, x) - Rf(ym, x) * VY(ym, x));

    // S/T(yy,xx): yy in [0,NY), xx in [0,NX]
    auto ST = [&](int yy, int xx, float& Sv, float& Tv) {
        int cm = wr(xx - 1, NX), c0 = wr(xx, NX);
        float gp = 0.25f * (GG(yy, cm) + GG(yy, c0) + GG(yy + 1, cm) + GG(yy + 1, c0));
        int fm = wr(xx - 1, NXU), fp = wr(xx + 1, NXU);
        float fpart = 0.5f * (FX(yy, fm) + FX(yy, fp)) * (1.0f / 24.0f);
        Sv = gp + fpart;
        Tv = gp - fpart;
    };
    auto VXY = [&](int yy, int xx) { // bar_xy(pad_x(v)), xx in [0,NX]
        int cm = wr(xx - 1, NX), c0 = wr(xx, NX);
        return 0.25f * (v[(z * NYV + yy) * NX + cm] + v[(z * NYV + yy) * NX + c0]
                      + v[(z * NYV + yy + 1) * NX + cm] + v[(z * NYV + yy + 1) * NX + c0]);
    };
    float S_a, T_a, S_b, T_b, S_c, T_c, S_d, T_d;
    ST(y0, x + 1, S_a, T_a);
    ST(ym, x,     S_b, T_b);
    ST(y0, x,     S_c, T_c);
    ST(ym, x + 1, S_d, T_d);
    float term3 = S_a * VXY(y0, x + 1) - S_b * VXY(ym, x);
    float term4 = T_c * VXY(y0, x) - T_d * VXY(ym, x + 1);
    float advec = 0.5f * (term1 + term2 + term3 + term4);

    // trans
    float pw = pi[ym * NX + xm] * w[(z * NY + ym) * NX + xm]
             + pi[y0 * NX + xm] * w[(z * NY + y0) * NX + xm]
             + pi[ym * NX + xp] * w[(z * NY + ym) * NX + xp]
             + pi[y0 * NX + xp] * w[(z * NY + y0) * NX + xp];
    float piw = DA8F * 0.25f * pw;
    float vbz = 0.5f * ((z > 0 ? v[((z - 1) * NYV + y) * NX + x] : 0.f)
                      + (z + 1 < NZ ? v[((z + 1) * NYV + y) * NX + x] : 0.f));
    float trans = -(piw * vbz * 0.5f) * RDZF;

    // press
    float dphi = phi[(z * NY + y0) * NX + x] - phi[(z * NY + ym) * NX + x];
    float dpi  = pi[y0 * NX + x] - pi[ym * NX + x];
    float vc   = (sigma[z] * Pu[z] - Pp[z] * sigma[z]) * RDZF;
    float vbar = 0.5f * (th[(z * NY + ym) * NX + x] + th[(z * NY + y0) * NX + x]) * vc;
    float press = DXF * (dphi * dpi * 0.5f + dpi * 0.5f * CPDF * vbar);

    // diff: laplacian of v, y wraps over NYV
    int yvm = wr(y - 1, NYV), yvp = wr(y + 1, NYV);
    float vcur = v[(z * NYV + y) * NX + x];
    float lap = (z + 1 < NZ ? v[((z + 1) * NYV + y) * NX + x] : 0.f)
              + (z > 0 ? v[((z - 1) * NYV + y) * NX + x] : 0.f)
              + v[(z * NYV + yvp) * NX + x] + v[(z * NYV + yvm) * NX + x]
              + v[(z * NYV + y) * NX + xp] + v[(z * NYV + y) * NX + xm] - 6.0f * vcur;
    float diffv = DIFFF * lap;

    float p0da = DA8F * 0.25f * (pi0[ym * NX + xm] + pi0[y0 * NX + xm] + pi0[ym * NX + xp] + pi0[y0 * NX + xp]);
    float p1da = DA8F * 0.25f * (pi1[ym * NX + xm] + pi1[y0 * NX + xm] + pi1[ym * NX + xp] + pi1[y0 * NX + xp]);
    out[(z * NYV + y) * NX + x] = (p0da * v0[(z * NYV + y) * NX + x] + dt * (advec + trans + press + diffv)) / p1da;
}

extern "C" void kernel_launch(void* const* d_in, const int* in_sizes, int n_in,
                              void* d_out, int out_size, void* d_ws, size_t ws_size,
                              hipStream_t stream) {
    const float* pi    = (const float*)d_in[0];
    const float* theta = (const float*)d_in[1];
    const float* u     = (const float*)d_in[2];
    const float* v     = (const float*)d_in[3];
    const float* w     = (const float*)d_in[4];
    const float* phi   = (const float*)d_in[5];
    const float* Y     = (const float*)d_in[6];
    const float* sigma = (const float*)d_in[8];
    const float* P_    = (const float*)d_in[9];
    const float* P     = (const float*)d_in[10];
    const float* dtp   = (const float*)d_in[12];

    float* out_pi = (float*)d_out;
    float* out_th = out_pi + NY * NX;
    float* out_u  = out_th + NZ * NY * NX;
    float* out_v  = out_u + NZ * NY * NXU;

    float* ws   = (float*)d_ws;
    float* w_pi = ws;
    float* w_th = w_pi + NY * NX;
    float* w_u  = w_th + NZ * NY * NX;
    float* w_v  = w_u + NZ * NY * NXU;
    float* cyt  = w_v + NZ * NYV * NX;

    dim3 blk(256);
    dim3 gpi((NX + 255) / 256, NY);
    dim3 gth((NX + 255) / 256, NY, NZ);
    dim3 gu((NXU + 255) / 256, NY, NZ);
    dim3 gv((NX + 255) / 256, NYV, NZ);

    k_cosy<<<1, 512, 0, stream>>>(Y, cyt);

    // step 1: current = originals, state0 = originals, dt/2
    k_pi1<<<gpi, blk, 0, stream>>>(pi, u, v, cyt, pi, dtp, 0.5f, w_pi);
    k_theta1<<<gth, blk, 0, stream>>>(pi, theta, u, v, cyt, w, pi, theta, w_pi, dtp, 0.5f, w_th);
    k_u1<<<gu, blk, 0, stream>>>(pi, theta, u, v, cyt, w, phi, pi, u, w_pi, sigma, P_, P, dtp, 0.5f, w_u);
    k_v1<<<gv, blk, 0, stream>>>(pi, theta, u, v, cyt, w, phi, pi, v, w_pi, sigma, P_, P, dtp, 0.5f, w_v);

    // step 2: current = intermediates, state0 = originals, dt
    k_pi1<<<gpi, blk, 0, stream>>>(w_pi, w_u, w_v, cyt, pi, dtp, 1.0f, out_pi);
    k_theta1<<<gth, blk, 0, stream>>>(w_pi, w_th, w_u, w_v, cyt, w, pi, theta, out_pi, dtp, 1.0f, out_th);
    k_u1<<<gu, blk, 0, stream>>>(w_pi, w_th, w_u, w_v, cyt, w, phi, pi, u, out_pi, sigma, P_, P, dtp, 1.0f, out_u);
    k_v1<<<gv, blk, 0, stream>>>(w_pi, w_th, w_u, w_v, cyt, w, phi, pi, v, out_pi, sigma, P_, P, dtp, 1.0f, out_v);
}

// Round 2
// 807.457 us; speedup vs baseline: 2.7774x; 2.7774x over previous
//
#include <hip/hip_runtime.h>
#include <math.h>

#define NZ 32
#define NY 360
#define NX 720
#define NXU (NX + 1)   // 721
#define NYV (NY + 1)   // 361
#define SU (NY * NXU)  // u z-stride
#define SV (NYV * NX)  // v z-stride
#define SW (NY * NX)   // scalar-field z-stride
#define ZSPLIT 2
#define ZB (NZ / ZSPLIT)

static constexpr double PI_D = 3.14159265358979323846;
static constexpr double RE_D = 6400000.0;
static constexpr double DX_D = 2.0 * PI_D / NX;
static constexpr double DY_D = PI_D / NY;
static constexpr double DA_D = RE_D * DX_D * (RE_D * DY_D);

constexpr float FXC   = (float)(0.25 * RE_D * DY_D);
constexpr float GXC   = (float)(0.25 * RE_D * DX_D);
constexpr float DAF   = (float)DA_D;
constexpr float DA8F  = (float)(DA_D / 8.0);
constexpr float DYF   = (float)DY_D;
constexpr float DXF   = (float)DX_D;
constexpr float CPDF  = 1004.67f;
constexpr float DIFFF = 1.0e9f;
constexpr float RDZF  = 32.0f;
constexpr float DZF   = 0.03125f;
constexpr float K1    = 0.25f / 12.0f;
constexpr float K2u   = 0.25f / 24.0f;
constexpr float K2v   = 0.5f / 24.0f;

__device__ __forceinline__ int wr(int i, int n) {
    return i < 0 ? i + n : (i >= n ? i - n : i);
}

// bijective XCD-chunked swizzle (m204 form)
__device__ __forceinline__ int xcd_swz(int bid, int nwg) {
    int q = nwg >> 3, r = nwg & 7;
    int xcd = bid & 7, off = bid >> 3;
    return (xcd < r ? xcd * (q + 1) : r * (q + 1) + (xcd - r) * q) + off;
}

__global__ void k_cosy(const float* __restrict__ Y, float* __restrict__ cy) {
    int t = threadIdx.x;
    if (t < NYV) cy[t] = cosf(Y[t]);
}

__global__ void k_pi1(const float* __restrict__ pi, const float* __restrict__ u,
                      const float* __restrict__ v, const float* __restrict__ cy,
                      const float* __restrict__ pi0, const float* __restrict__ dtp,
                      float dtmul, float* __restrict__ out) {
    int x = blockIdx.x * blockDim.x + threadIdx.x;
    int y = blockIdx.y;
    if (x >= NX) return;
    float dt = dtp[0] * dtmul;
    int xm = wr(x - 1, NX), xp = wr(x + 1, NX);
    float pc  = pi[y * NX + x];
    float a_m = pi[y * NX + xm] + pc;
    float a_p = pc + pi[y * NX + xp];
    float g_lo = (pi[wr(y - 1, NY) * NX + x] + pc) * cy[y];
    float g_hi = (pc + pi[wr(y + 1, NY) * NX + x]) * cy[y + 1];
    float acc = 0.f;
    for (int z = 0; z < NZ; ++z) {
        float fxm = FXC * a_m * u[((size_t)z * NY + y) * NXU + x];
        float fxp = FXC * a_p * u[((size_t)z * NY + y) * NXU + x + 1];
        float glo = GXC * g_lo * v[((size_t)z * NYV + y) * NX + x];
        float ghi = GXC * g_hi * v[((size_t)z * NYV + y + 1) * NX + x];
        acc += ((fxp - fxm) + (ghi - glo)) * DZF;
    }
    out[y * NX + x] = pi0[y * NX + x] - dt / DAF * acc;
}

__global__ void k_theta1(const float* __restrict__ pi, const float* __restrict__ th,
                         const float* __restrict__ u, const float* __restrict__ v,
                         const float* __restrict__ cy, const float* __restrict__ w,
                         const float* __restrict__ pi0, const float* __restrict__ th0,
                         const float* __restrict__ pi1, const float* __restrict__ dtp,
                         float dtmul, float* __restrict__ out) {
    const int nwg = 3 * NY * ZSPLIT;
    int wgid = xcd_swz(blockIdx.x, nwg);
    int bx = wgid % 3; int tmp = wgid / 3;
    int y = tmp % NY; int bz = tmp / NY;
    int x = bx * 256 + threadIdx.x;
    if (x >= NX) return;
    float dt = dtp[0] * dtmul;
    int xm = wr(x - 1, NX), xp = wr(x + 1, NX);
    int ym = wr(y - 1, NY), yp = wr(y + 1, NY);
    float pc  = pi[y * NX + x];
    float a_m = FXC * (pi[y * NX + xm] + pc);
    float a_p = FXC * (pc + pi[y * NX + xp]);
    float g_lo = GXC * (pi[ym * NX + x] + pc) * cy[y];
    float g_hi = GXC * (pc + pi[yp * NX + x]) * cy[y + 1];
    float rp1  = 1.0f / pi1[y * NX + x];
    float c0v  = pi0[y * NX + x] * rp1;
    float cvert = pc * DAF * RDZF;
    float cdt  = dt / DAF * rp1;
    int base = y * NX + x;
    int z0 = bz * ZB, z1 = z0 + ZB;
    float tc  = th[(size_t)z0 * SW + base];
    float tzm = (z0 > 0) ? th[(size_t)(z0 - 1) * SW + base] : 0.f;
    for (int z = z0; z < z1; ++z) {
        const float* tb = th + (size_t)z * SW;
        float tzp = (z + 1 < NZ) ? tb[SW + base] : 0.f;
        float t_xm = tb[y * NX + xm], t_xp = tb[y * NX + xp];
        float t_ym = tb[ym * NX + x], t_yp = tb[yp * NX + x];
        float fx0 = a_m * u[((size_t)z * NY + y) * NXU + x];
        float fx1 = a_p * u[((size_t)z * NY + y) * NXU + x + 1];
        float gg0 = g_lo * v[((size_t)z * NYV + y) * NX + x];
        float gg1 = g_hi * v[((size_t)z * NYV + y + 1) * NX + x];
        float adv = (fx1 * 0.5f * (tc + t_xp) - fx0 * 0.5f * (t_xm + tc)
                   + gg1 * 0.5f * (tc + t_yp) - gg0 * 0.5f * (t_ym + tc)) * 0.5f;
        float th0v = th0[(size_t)z * SW + base];
        float vert = cvert * (w[(size_t)z * SW + base] * th0v);
        float lap = tzp + tzm + t_yp + t_ym + t_xp + t_xm - 6.0f * tc;
        out[(size_t)z * SW + base] = c0v * th0v + cdt * (adv + vert + DIFFF * lap);
        tzm = tc; tc = tzp;
    }
}

__global__ void k_u1(const float* __restrict__ pi, const float* __restrict__ th,
                     const float* __restrict__ u, const float* __restrict__ v,
                     const float* __restrict__ cy, const float* __restrict__ w,
                     const float* __restrict__ phi, const float* __restrict__ pi0,
                     const float* __restrict__ u0, const float* __restrict__ pi1,
                     const float* __restrict__ sigma, const float* __restrict__ Pu,
                     const float* __restrict__ Pp, const float* __restrict__ dtp,
                     float dtmul, float* __restrict__ out) {
    const int nwg = 3 * NY * ZSPLIT;
    int wgid = xcd_swz(blockIdx.x, nwg);
    int bx = wgid % 3; int tmp = wgid / 3;
    int y = tmp % NY; int bz = tmp / NY;
    int x = bx * 256 + threadIdx.x;
    if (x >= NXU) return;
    float dt = dtp[0] * dtmul;

    int x0 = wr(x, NX), xm = wr(x - 1, NX);
    int ym = wr(y - 1, NY), yp = wr(y + 1, NY);
    // u/FX columns (all valid in [0,720])
    int c0 = xm, c1 = xm + 1, c2 = x0, c3 = x0 + 1;
    // GG rows
    int g0 = (y == 0) ? NY : (y - 1);
    int g1 = y, g2 = y + 1;
    int g3 = (y + 2 > NY) ? (y + 2 - NYV) : (y + 2);

    // z-invariant FX coefficients Px[row][col], rows {ym,y,yp}
    int rows3[3] = {ym, y, yp};
    int cols4[4] = {c0, c1, c2, c3};
    float Px[3][4];
#pragma unroll
    for (int r = 0; r < 3; ++r) {
        int rb = rows3[r] * NX;
#pragma unroll
        for (int c = 0; c < 4; ++c) {
            int cc = cols4[c];
            Px[r][c] = FXC * (pi[rb + wr(cc - 1, NX)] + pi[rb + wr(cc, NX)]);
        }
    }
    // z-invariant GG coefficients Pg[row][col], rows {g0..g3}, cols {xm,x0}
    int grows[4] = {g0, g1, g2, g3};
    float Pg[4][2];
    int ovr[4];
#pragma unroll
    for (int j = 0; j < 4; ++j) {
        int ra = wr(grows[j] - 1, NY) * NX;
        int rb = wr(grows[j], NY) * NX;
        float cj = cy[grows[j]];
        Pg[j][0] = GXC * (pi[ra + xm] + pi[rb + xm]) * cj;
        Pg[j][1] = GXC * (pi[ra + x0] + pi[rb + x0]) * cj;
        ovr[j] = grows[j] * NX;
    }
    // trans / press / denom hoists
    float pimm = pi[ym * NX + xm], pim0 = pi[ym * NX + x0];
    float pipm = pi[yp * NX + xm], pip0 = pi[yp * NX + x0];
    float dpi  = pi[y * NX + x0] - pi[y * NX + xm];
    float p0da = DA8F * 0.25f * (pi0[ym * NX + xm] + pi0[ym * NX + x0] + pi0[yp * NX + xm] + pi0[yp * NX + x0]);
    float p1da = DA8F * 0.25f * (pi1[ym * NX + xm] + pi1[ym * NX + x0] + pi1[yp * NX + xm] + pi1[yp * NX + x0]);
    float rp1da = 1.0f / p1da;

    int ou0 = ym * NXU, ou1 = y * NXU, ou2 = yp * NXU;
    int ow0 = ym * NX, ow1 = yp * NX;
    int uidx = ou1 + x;

    int z0 = bz * ZB, z1 = z0 + ZB;
    float uc  = u[(size_t)z0 * SU + uidx];
    float uzm = (z0 > 0) ? u[(size_t)(z0 - 1) * SU + uidx] : 0.f;

    for (int z = z0; z < z1; ++z) {
        const float* ub = u + (size_t)z * SU;
        const float* vb = v + (size_t)z * SV;
        const float* wb = w + (size_t)z * SW;
        float uzp = (z + 1 < NZ) ? ub[SU + uidx] : 0.f;

        // u tile
        float U00 = ub[ou0 + c0], U01 = ub[ou0 + c1], U02 = ub[ou0 + c2], U03 = ub[ou0 + c3];
        float U10 = ub[ou1 + c0], U11 = ub[ou1 + c1], U12 = ub[ou1 + c2], U13 = ub[ou1 + c3];
        float U20 = ub[ou2 + c0], U21 = ub[ou2 + c1], U22 = ub[ou2 + c2], U23 = ub[ou2 + c3];
        float Ux0 = (x < NX) ? U02 : ub[ou0 + x];
        float Ux2 = (x < NX) ? U22 : ub[ou2 + x];
        float Ux1 = uc;
        float ulm = (x > 0)  ? U10 : ub[ou1 + NX]; // wrap mod NXU
        float ulp = (x < NX) ? U13 : U12;          // x==720: xup==0==c2

        // FX values
        float F00 = Px[0][0]*U00, F01 = Px[0][1]*U01, F02 = Px[0][2]*U02, F03 = Px[0][3]*U03;
        float F10 = Px[1][0]*U10, F11 = Px[1][1]*U11, F12 = Px[1][2]*U12, F13 = Px[1][3]*U13;
        float F20 = Px[2][0]*U20, F21 = Px[2][1]*U21, F22 = Px[2][2]*U22, F23 = Px[2][3]*U23;
        // GG values
        float G00 = Pg[0][0]*vb[ovr[0] + xm], G01 = Pg[0][1]*vb[ovr[0] + x0];
        float G10 = Pg[1][0]*vb[ovr[1] + xm], G11 = Pg[1][1]*vb[ovr[1] + x0];
        float G20 = Pg[2][0]*vb[ovr[2] + xm], G21 = Pg[2][1]*vb[ovr[2] + x0];
        float G30 = Pg[3][0]*vb[ovr[3] + xm], G31 = Pg[3][1]*vb[ovr[3] + x0];

        float B0 = (F02 + F03 + F22 + F23) * K1;
        float Bm = (F00 + F01 + F20 + F21) * K1;
        float UB0 = 0.5f * (U12 + U13), UBm = 0.5f * (U10 + U11);
        float term1 = Bm * UBm - B0 * UB0;

        float Cp = (G10 + G11 + G30 + G31) * K1;
        float C0 = (G00 + G01 + G20 + G21) * K1;
        float UYp = 0.5f * (Ux1 + Ux2), UY0 = 0.5f * (Ux0 + Ux1);
        float term2 = C0 * UY0 - Cp * UYp;

        float D_a = 0.5f * (G11 + G31) + (F12 + F13 + F22 + F23) * K2u;
        float D_b = 0.5f * (G00 + G20) + (F00 + F01 + F10 + F11) * K2u;
        float E_c = 0.5f * (G10 + G30) - (F10 + F11 + F20 + F21) * K2u;
        float E_d = 0.5f * (G01 + G21) - (F02 + F03 + F12 + F13) * K2u;
        float UXY_a = 0.25f * (U12 + U13 + U22 + U23);
        float UXY_b = 0.25f * (U00 + U01 + U10 + U11);
        float UXY_c = 0.25f * (U10 + U11 + U20 + U21);
        float UXY_d = 0.25f * (U02 + U03 + U12 + U13);
        float term3 = D_a * UXY_a - D_b * UXY_b;
        float term4 = E_c * UXY_c - E_d * UXY_d;
        float advec = 0.5f * (term1 + term2 + term3 + term4);

        float pw = pimm * wb[ow0 + xm] + pim0 * wb[ow0 + x0]
                 + pipm * wb[ow1 + xm] + pip0 * wb[ow1 + x0];
        float piw = DA8F * 0.25f * pw;
        float ubz = 0.5f * (uzm + uzp);
        float trans = -(piw * ubz * 0.5f) * RDZF;

        float dphi = phi[(size_t)z * SW + y * NX + x0] - phi[(size_t)z * SW + y * NX + xm];
        float vc   = sigma[z] * (Pu[z] - Pp[z]) * RDZF;
        float vbar = 0.5f * (th[(size_t)z * SW + y * NX + xm] + th[(size_t)z * SW + y * NX + x0]) * vc;
        float press = DYF * (dphi * dpi * 0.5f + dpi * 0.5f * CPDF * vbar);

        float lap = uzp + uzm + Ux2 + Ux0 + ulp + ulm - 6.0f * uc;
        float diffv = DIFFF * lap;

        out[(size_t)z * SU + uidx] = (p0da * u0[(size_t)z * SU + uidx]
                                      + dt * (advec + trans + press + diffv)) * rp1da;
        uzm = uc; uc = uzp;
    }
}

__global__ void k_v1(const float* __restrict__ pi, const float* __restrict__ th,
                     const float* __restrict__ u, const float* __restrict__ v,
                     const float* __restrict__ cy, const float* __restrict__ w,
                     const float* __restrict__ phi, const float* __restrict__ pi0,
                     const float* __restrict__ v0, const float* __restrict__ pi1,
                     const float* __restrict__ sigma, const float* __restrict__ Pu,
                     const float* __restrict__ Pp, const float* __restrict__ dtp,
                     float dtmul, float* __restrict__ out) {
    const int nwg = 3 * NYV * ZSPLIT;
    int wgid = xcd_swz(blockIdx.x, nwg);
    int bx = wgid % 3; int tmp = wgid / 3;
    int y = tmp % NYV; int bz = tmp / NYV;
    int x = bx * 256 + threadIdx.x;
    if (x >= NX) return;
    float dt = dtp[0] * dtmul;

    int xm = wr(x - 1, NX), xp = wr(x + 1, NX);
    int y0 = wr(y, NY), ym = wr(y - 1, NY);
    // FX (u) columns mod NXU
    int cq0 = (x == 0) ? NX : (x - 1);          // wr(x-1,NXU)
    int cq1 = x, cq2 = x + 1;                   // <=720
    int cq3 = (x + 2 > NX) ? (x + 2 - NXU) : (x + 2); // wr(x+2,NXU)
    // GG rows
    int gr0 = ym, gr1 = ym + 1, gr2 = y0, gr3 = y0 + 1;

    // z-invariant FX coeffs, rows {ym,y0}
    int rws[2] = {ym, y0};
    int cqs[4] = {cq0, cq1, cq2, cq3};
    float Pxv[2][4];
#pragma unroll
    for (int r = 0; r < 2; ++r) {
        int rb = rws[r] * NX;
#pragma unroll
        for (int c = 0; c < 4; ++c) {
            int cc = cqs[c];
            Pxv[r][c] = FXC * (pi[rb + wr(cc - 1, NX)] + pi[rb + wr(cc, NX)]);
        }
    }
    // z-invariant GG coeffs, rows {gr0..gr3}, cols {xm,x,xp}
    int grs[4] = {gr0, gr1, gr2, gr3};
    int cls[3] = {xm, x, xp};
    float Pgv[4][3];
    int ovr[4];
#pragma unroll
    for (int j = 0; j < 4; ++j) {
        int ra = wr(grs[j] - 1, NY) * NX;
        int rb = wr(grs[j], NY) * NX;
        float cj = cy[grs[j]];
#pragma unroll
        for (int c = 0; c < 3; ++c)
            Pgv[j][c] = GXC * (pi[ra + cls[c]] + pi[rb + cls[c]]) * cj;
        ovr[j] = grs[j] * NX;
    }
    float pvmm = pi[ym * NX + xm], pv0m = pi[y0 * NX + xm];
    float pvmp = pi[ym * NX + xp], pv0p = pi[y0 * NX + xp];
    float dpi  = pi[y0 * NX + x] - pi[ym * NX + x];
    float p0da = DA8F * 0.25f * (pi0[ym * NX + xm] + pi0[y0 * NX + xm] + pi0[ym * NX + xp] + pi0[y0 * NX + xp]);
    float p1da = DA8F * 0.25f * (pi1[ym * NX + xm] + pi1[y0 * NX + xm] + pi1[ym * NX + xp] + pi1[y0 * NX + xp]);
    float rp1da = 1.0f / p1da;

    int yvm = (y == 0) ? NY : (y - 1);   // wr(y-1,NYV)
    int yvp = (y == NY) ? 0 : (y + 1);   // wr(y+1,NYV)
    int ou_m = ym * NXU, ou_0 = y0 * NXU;
    int vidx = y * NX + x;

    int z0 = bz * ZB, z1 = z0 + ZB;
    float vc_r = v[(size_t)z0 * SV + vidx];
    float vzm  = (z0 > 0) ? v[(size_t)(z0 - 1) * SV + vidx] : 0.f;

    for (int z = z0; z < z1; ++z) {
        const float* ub = u + (size_t)z * SU;
        const float* vb = v + (size_t)z * SV;
        const float* wb = w + (size_t)z * SW;
        float vzp = (z + 1 < NZ) ? vb[SV + vidx] : 0.f;

        // FX values
        float F00 = Pxv[0][0]*ub[ou_m + cq0], F01 = Pxv[0][1]*ub[ou_m + cq1];
        float F02 = Pxv[0][2]*ub[ou_m + cq2], F03 = Pxv[0][3]*ub[ou_m + cq3];
        float F10 = Pxv[1][0]*ub[ou_0 + cq0], F11 = Pxv[1][1]*ub[ou_0 + cq1];
        float F12 = Pxv[1][2]*ub[ou_0 + cq2], F13 = Pxv[1][3]*ub[ou_0 + cq3];
        // v tile rows gr0..gr3, cols {xm,x,xp}
        float V00 = vb[ovr[0] + xm], V01 = vb[ovr[0] + x], V02 = vb[ovr[0] + xp];
        float V10 = vb[ovr[1] + xm], V11 = vb[ovr[1] + x], V12 = vb[ovr[1] + xp];
        float V20 = vb[ovr[2] + xm], V21 = vb[ovr[2] + x], V22 = vb[ovr[2] + xp];
        float V30 = vb[ovr[3] + xm], V31 = vb[ovr[3] + x], V32 = vb[ovr[3] + xp];
        // GG values
        float G00 = Pgv[0][0]*V00, G01 = Pgv[0][1]*V01, G02 = Pgv[0][2]*V02;
        float G10 = Pgv[1][0]*V10, G11 = Pgv[1][1]*V11, G12 = Pgv[1][2]*V12;
        float G20 = Pgv[2][0]*V20, G21 = Pgv[2][1]*V21, G22 = Pgv[2][2]*V22;
        float G30 = Pgv[3][0]*V30, G31 = Pgv[3][1]*V31, G32 = Pgv[3][2]*V32;

        // VX row y raw (block-uniform branch)
        float vy_m, vy_p;
        if (y < NY) { vy_m = V20; vy_p = V22; }
        else { vy_m = vb[y * NX + xm]; vy_p = vb[y * NX + xp]; }
        float vy_0 = vc_r;

        float Q_p = (F01 + F11 + F03 + F13) * K1;
        float Q_0 = (F00 + F10 + F02 + F12) * K1;
        float VX_p = 0.5f * (vy_0 + vy_p), VX_0 = 0.5f * (vy_m + vy_0);
        float term1 = Q_0 * VX_0 - Q_p * VX_p;

        float R_0 = (G20 + G30 + G22 + G32) * K1;
        float R_m = (G00 + G10 + G02 + G12) * K1;
        float VY_0 = 0.5f * (V21 + V31), VY_m = 0.5f * (V01 + V11);
        float term2 = R_m * VY_m - R_0 * VY_0;

        float S_a = 0.25f * (G21 + G22 + G31 + G32) + (F11 + F13) * K2v;
        float S_b = 0.25f * (G00 + G01 + G10 + G11) + (F00 + F02) * K2v;
        float T_c = 0.25f * (G20 + G21 + G30 + G31) - (F10 + F12) * K2v;
        float T_d = 0.25f * (G01 + G02 + G11 + G12) - (F01 + F03) * K2v;
        float VXY_a = 0.25f * (V21 + V22 + V31 + V32);
        float VXY_b = 0.25f * (V00 + V01 + V10 + V11);
        float VXY_c = 0.25f * (V20 + V21 + V30 + V31);
        float VXY_d = 0.25f * (V01 + V02 + V11 + V12);
        float term3 = S_a * VXY_a - S_b * VXY_b;
        float term4 = T_c * VXY_c - T_d * VXY_d;
        float advec = 0.5f * (term1 + term2 + term3 + term4);

        float pw = pvmm * wb[ym * NX + xm] + pv0m * wb[y0 * NX + xm]
                 + pvmp * wb[ym * NX + xp] + pv0p * wb[y0 * NX + xp];
        float piw = DA8F * 0.25f * pw;
        float vbz = 0.5f * (vzm + vzp);
        float trans = -(piw * vbz * 0.5f) * RDZF;

        float dphi = phi[(size_t)z * SW + y0 * NX + x] - phi[(size_t)z * SW + ym * NX + x];
        float vcz  = sigma[z] * (Pu[z] - Pp[z]) * RDZF;
        float vbar = 0.5f * (th[(size_t)z * SW + ym * NX + x] + th[(size_t)z * SW + y0 * NX + x]) * vcz;
        float press = DXF * (dphi * dpi * 0.5f + dpi * 0.5f * CPDF * vbar);

        // laplacian neighbors in y (mod NYV), block-uniform branches
        float vlm = (y > 0)  ? V01 : vb[NY * NX + x];  // row 360
        float vlp = (y < NY) ? V31 : vb[0 * NX + x];   // row 0
        float lap = vzp + vzm + vlp + vlm + vy_p + vy_m - 6.0f * vc_r;
        float diffv = DIFFF * lap;

        out[(size_t)z * SV + vidx] = (p0da * v0[(size_t)z * SV + vidx]
                                      + dt * (advec + trans + press + diffv)) * rp1da;
        vzm = vc_r; vc_r = vzp;
    }
}

extern "C" void kernel_launch(void* const* d_in, const int* in_sizes, int n_in,
                              void* d_out, int out_size, void* d_ws, size_t ws_size,
                              hipStream_t stream) {
    const float* pi    = (const float*)d_in[0];
    const float* theta = (const float*)d_in[1];
    const float* u     = (const float*)d_in[2];
    const float* v     = (const float*)d_in[3];
    const float* w     = (const float*)d_in[4];
    const float* phi   = (const float*)d_in[5];
    const float* Y     = (const float*)d_in[6];
    const float* sigma = (const float*)d_in[8];
    const float* P_    = (const float*)d_in[9];
    const float* P     = (const float*)d_in[10];
    const float* dtp   = (const float*)d_in[12];

    float* out_pi = (float*)d_out;
    float* out_th = out_pi + NY * NX;
    float* out_u  = out_th + NZ * NY * NX;
    float* out_v  = out_u + NZ * NY * NXU;

    float* ws   = (float*)d_ws;
    float* w_pi = ws;
    float* w_th = w_pi + NY * NX;
    float* w_u  = w_th + NZ * NY * NX;
    float* w_v  = w_u + NZ * NY * NXU;
    float* cyt  = w_v + NZ * NYV * NX;

    dim3 blk(256);
    dim3 gpi((NX + 255) / 256, NY);
    dim3 gth(3 * NY * ZSPLIT);
    dim3 gu(3 * NY * ZSPLIT);
    dim3 gv(3 * NYV * ZSPLIT);

    k_cosy<<<1, 512, 0, stream>>>(Y, cyt);

    // step 1: current = originals, state0 = originals, dt/2
    k_pi1<<<gpi, blk, 0, stream>>>(pi, u, v, cyt, pi, dtp, 0.5f, w_pi);
    k_theta1<<<gth, blk, 0, stream>>>(pi, theta, u, v, cyt, w, pi, theta, w_pi, dtp, 0.5f, w_th);
    k_u1<<<gu, blk, 0, stream>>>(pi, theta, u, v, cyt, w, phi, pi, u, w_pi, sigma, P_, P, dtp, 0.5f, w_u);
    k_v1<<<gv, blk, 0, stream>>>(pi, theta, u, v, cyt, w, phi, pi, v, w_pi, sigma, P_, P, dtp, 0.5f, w_v);

    // step 2: current = intermediates, state0 = originals, dt
    k_pi1<<<gpi, blk, 0, stream>>>(w_pi, w_u, w_v, cyt, pi, dtp, 1.0f, out_pi);
    k_theta1<<<gth, blk, 0, stream>>>(w_pi, w_th, w_u, w_v, cyt, w, pi, theta, out_pi, dtp, 1.0f, out_th);
    k_u1<<<gu, blk, 0, stream>>>(w_pi, w_th, w_u, w_v, cyt, w, phi, pi, u, out_pi, sigma, P_, P, dtp, 1.0f, out_u);
    k_v1<<<gv, blk, 0, stream>>>(w_pi, w_th, w_u, w_v, cyt, w, phi, pi, v, out_pi, sigma, P_, P, dtp, 1.0f, out_v);
}